// Round 6
// baseline (927.711 us; speedup 1.0000x reference)
//
#include <hip/hip_runtime.h>
#include <math.h>

namespace {

constexpr int BB  = 32;    // batch
constexpr int LL  = 1024;  // sequence length
constexpr int INP = 600;
constexpr int HID = 200;
constexpr int RS  = BB * LL;   // 32768 rows per stream
constexpr int DPAD = 640;      // padded d-dim for bf16 transposed s
constexpr int KP1 = 640;       // padded K for layer1 (INP=600 -> 640)
constexpr int KP2 = 256;       // padded K for layer2 / e (HID=200 -> 256)

constexpr int BM = 128, BN = 128, KT = 8;   // (fallback path tiles)

typedef __attribute__((ext_vector_type(8))) short short8v;           // bf16x8 fragment
typedef __attribute__((ext_vector_type(4))) float f32x4;

__device__ __forceinline__ float relu(float x) { return fmaxf(x, 0.f); }

__device__ __forceinline__ unsigned short f2bf(float x) {
  union { float f; unsigned int u; } v; v.f = x;
  unsigned int r = v.u + 0x7FFFu + ((v.u >> 16) & 1u);   // RNE
  return (unsigned short)(r >> 16);
}
__device__ __forceinline__ float bf2f(unsigned short h) {
  union { unsigned int u; float f; } v; v.u = ((unsigned int)h) << 16;
  return v.f;
}

// async global->LDS, 16B per lane; LDS dest = wave-uniform base + lane*16
__device__ __forceinline__ void gload16(const void* g, void* l) {
  __builtin_amdgcn_global_load_lds((const __attribute__((address_space(1))) void*)g,
                                   (__attribute__((address_space(3))) void*)l, 16, 0, 0);
}

// ============ presplit: s[2][RS][600] fp32 -> sp_hi/lo[2][RS][640] bf16, zero-padded ============
__global__ __launch_bounds__(256) void presplit(
    const float* __restrict__ S1, const float* __restrict__ S2,
    unsigned short* __restrict__ Hi, unsigned short* __restrict__ Lo)
{
  const long idx = (long)blockIdx.x * 256 + threadIdx.x;   // one 4-col quad each
  const long row = idx / 160;
  const int  c4  = (int)(idx - row * 160) * 4;
  const float* __restrict__ src = (row < RS) ? (S1 + row * (size_t)INP)
                                             : (S2 + (row - RS) * (size_t)INP);
  float4 v = make_float4(0.f, 0.f, 0.f, 0.f);
  if (c4 < INP) v = *(const float4*)(src + c4);
  ushort4 h4, l4;
  h4.x = f2bf(v.x); l4.x = f2bf(v.x - bf2f(h4.x));
  h4.y = f2bf(v.y); l4.y = f2bf(v.y - bf2f(h4.y));
  h4.z = f2bf(v.z); l4.z = f2bf(v.z - bf2f(h4.z));
  h4.w = f2bf(v.w); l4.w = f2bf(v.w - bf2f(h4.w));
  *(ushort4*)(Hi + row * (size_t)KP1 + c4) = h4;
  *(ushort4*)(Lo + row * (size_t)KP1 + c4) = l4;
}

// ============ W transpose + split prep: W[K][200] fp32 -> Wt_hi/lo[256][KP] bf16, zero-pad ======
__global__ __launch_bounds__(256) void wt_prep(
    const float* __restrict__ W, unsigned short* __restrict__ Whi, unsigned short* __restrict__ Wlo,
    int K, int KP)
{
  const int k = blockIdx.x * 256 + threadIdx.x;
  const int n = blockIdx.y;              // 0..255 (rows >=200 zero)
  if (k >= KP) return;
  float v = (k < K && n < HID) ? W[(size_t)k * HID + n] : 0.f;
  unsigned short hi = f2bf(v);
  unsigned short lo = f2bf(v - bf2f(hi));
  Whi[(size_t)n * KP + k] = hi;
  Wlo[(size_t)n * KP + k] = lo;
}

// ============ split-bf16 MFMA GEMM, ALL operands pre-split, pure global_load_lds staging ========
// Tile 128x128, 4 waves (2x2), BK=64. LDS: 4 planes of 1024 int4 slots
// (Ahi | Alo | Bhi | Blo), slot = row*8 + (chunk ^ (row&7)); wave w DMAs plane w.
// SPLIT_OUT=true : Out = split(relu(acc+bias)) -> bf16 hi/lo, zeros for gn>=HID.
// SPLIT_OUT=false: OutF = acc (fp32, no guard).
template <bool SPLIT_OUT>
__global__ __launch_bounds__(256) void splitmm2(
    const unsigned short* __restrict__ Ahi, const unsigned short* __restrict__ Alo,
    long aZ, int lda,
    const unsigned short* __restrict__ Bhi, const unsigned short* __restrict__ Blo,
    long bZ, int ldb,
    int ksteps, const float* __restrict__ bias,
    unsigned short* __restrict__ OutHi, unsigned short* __restrict__ OutLo,
    float* __restrict__ OutF, int ldo, long oZ)
{
  __shared__ int4 sL[4096];
  const int z = blockIdx.z;
  const int m0 = blockIdx.x * 128, n0 = blockIdx.y * 128;
  const int tid = threadIdx.x, lane = tid & 63, w = tid >> 6;
  const int wr = w >> 1, wc = w & 1, fr = lane & 15, kg = lane >> 4;

  // wave-uniform staging plane
  const unsigned short* __restrict__ wbase =
      (w == 0) ? (Ahi + (size_t)z * aZ) :
      (w == 1) ? (Alo + (size_t)z * aZ) :
      (w == 2) ? (Bhi + (size_t)z * bZ) :
                 (Blo + (size_t)z * bZ);
  const int wrow0 = (w < 2) ? m0 : n0;
  const int wld   = (w < 2) ? lda : ldb;

  f32x4 acc[4][4];
#pragma unroll
  for (int mi = 0; mi < 4; ++mi)
#pragma unroll
    for (int ni = 0; ni < 4; ++ni) acc[mi][ni] = (f32x4){0.f, 0.f, 0.f, 0.f};

  for (int ks = 0; ks < ksteps; ++ks) {
    const int k0 = ks * 64;
    __syncthreads();
#pragma unroll
    for (int i = 0; i < 16; ++i) {
      const int s = w * 1024 + i * 64 + lane;
      const int rem = s & 1023, r = rem >> 3, kc = rem & 7;
      const int gc = kc ^ (r & 7);
      gload16(wbase + (size_t)(wrow0 + r) * wld + k0 + gc * 8,
              (char*)sL + (size_t)s * 16);
    }
    __syncthreads();
#pragma unroll
    for (int kk = 0; kk < 2; ++kk) {
      short8v ah[4], al[4], bh[4], bl[4];
#pragma unroll
      for (int mi = 0; mi < 4; ++mi) {
        const int row = wr * 64 + mi * 16 + fr;
        const int idx = row * 8 + ((kk * 4 + kg) ^ (row & 7));
        ah[mi] = *(const short8v*)&sL[idx];
        al[mi] = *(const short8v*)&sL[1024 + idx];
      }
#pragma unroll
      for (int ni = 0; ni < 4; ++ni) {
        const int row = wc * 64 + ni * 16 + fr;
        const int idx = row * 8 + ((kk * 4 + kg) ^ (row & 7));
        bh[ni] = *(const short8v*)&sL[2048 + idx];
        bl[ni] = *(const short8v*)&sL[3072 + idx];
      }
#pragma unroll
      for (int mi = 0; mi < 4; ++mi)
#pragma unroll
        for (int ni = 0; ni < 4; ++ni) {
          acc[mi][ni] = __builtin_amdgcn_mfma_f32_16x16x32_bf16(ah[mi], bh[ni], acc[mi][ni], 0, 0, 0);
          acc[mi][ni] = __builtin_amdgcn_mfma_f32_16x16x32_bf16(ah[mi], bl[ni], acc[mi][ni], 0, 0, 0);
          acc[mi][ni] = __builtin_amdgcn_mfma_f32_16x16x32_bf16(al[mi], bh[ni], acc[mi][ni], 0, 0, 0);
        }
    }
  }
  // ---- epilogue (C/D: col = lane&15, row = (lane>>4)*4 + reg)
#pragma unroll
  for (int ni = 0; ni < 4; ++ni) {
    const int gn = n0 + wc * 64 + ni * 16 + fr;
    if (SPLIT_OUT) {
      const bool valid = gn < HID;
      const float bs = valid ? bias[gn] : 0.f;
#pragma unroll
      for (int mi = 0; mi < 4; ++mi) {
#pragma unroll
        for (int r = 0; r < 4; ++r) {
          const int gm = m0 + wr * 64 + mi * 16 + kg * 4 + r;
          unsigned short hi = 0, lo = 0;
          if (valid) {
            float v = relu(acc[mi][ni][r] + bs);
            hi = f2bf(v);
            lo = f2bf(v - bf2f(hi));
          }
          OutHi[(size_t)z * oZ + (size_t)gm * ldo + gn] = hi;
          OutLo[(size_t)z * oZ + (size_t)gm * ldo + gn] = lo;
        }
      }
    } else {
#pragma unroll
      for (int mi = 0; mi < 4; ++mi) {
#pragma unroll
        for (int r = 0; r < 4; ++r) {
          const int gm = m0 + wr * 64 + mi * 16 + kg * 4 + r;
          OutF[(size_t)z * oZ + (size_t)gm * ldo + gn] = acc[mi][ni][r];
        }
      }
    }
  }
}

// ---------------- fused row stats + P_beta: one E read, bf16 P out ----------------
__global__ __launch_bounds__(256) void row_stats_pbeta(
    const float* __restrict__ E, const float* __restrict__ mask2,
    unsigned short* __restrict__ Pb)
{
  const int wid = threadIdx.x >> 6, lane = threadIdx.x & 63;
  const int r = blockIdx.x * 4 + wid;
  const int b = r >> 10;
  const float* __restrict__ row = E + (size_t)r * LL;
  const float* __restrict__ m2 = mask2 + b * LL;
  float v[16];
  float mx = -INFINITY;
#pragma unroll
  for (int i = 0; i < 4; ++i) {
    const int m = lane * 4 + i * 256;
    float4 e4 = *(const float4*)(row + m);
    float4 k4 = *(const float4*)(m2 + m);
    v[i * 4 + 0] = e4.x * k4.x; v[i * 4 + 1] = e4.y * k4.y;
    v[i * 4 + 2] = e4.z * k4.z; v[i * 4 + 3] = e4.w * k4.w;
    mx = fmaxf(mx, fmaxf(fmaxf(v[i * 4], v[i * 4 + 1]), fmaxf(v[i * 4 + 2], v[i * 4 + 3])));
  }
#pragma unroll
  for (int off = 32; off; off >>= 1) mx = fmaxf(mx, __shfl_xor(mx, off));
  float s = 0.f;
#pragma unroll
  for (int i = 0; i < 16; ++i) s += __expf(v[i] - mx);
#pragma unroll
  for (int off = 32; off; off >>= 1) s += __shfl_xor(s, off);
  const float ri = 1.f / s;
#pragma unroll
  for (int i = 0; i < 4; ++i) {
    const int m = lane * 4 + i * 256;
    ushort4 o;
    o.x = f2bf(__expf(v[i * 4 + 0] - mx) * ri);
    o.y = f2bf(__expf(v[i * 4 + 1] - mx) * ri);
    o.z = f2bf(__expf(v[i * 4 + 2] - mx) * ri);
    o.w = f2bf(__expf(v[i * 4 + 3] - mx) * ri);
    *(ushort4*)(Pb + (size_t)r * LL + m) = o;
  }
}

// ---------------- column stats (alpha softmax over l), two-pass ----------------
__global__ __launch_bounds__(256) void col_stats_p1(
    const float* __restrict__ E, const float* __restrict__ mask1,
    float* __restrict__ pmax, float* __restrict__ psum)
{
  const int b = blockIdx.z, lc = blockIdx.y;
  const int m = blockIdx.x * 256 + threadIdx.x;
  const float* __restrict__ e = E + (size_t)b * LL * LL;
  const float* __restrict__ m1 = mask1 + b * LL;
  float mx = -INFINITY, s = 0.f;
#pragma unroll 4
  for (int l = lc * 256; l < lc * 256 + 256; ++l) {
    const float v = e[(size_t)l * LL + m] * m1[l];
    if (v > mx) { s = s * __expf(mx - v) + 1.f; mx = v; }
    else        { s += __expf(v - mx); }
  }
  const int idx = (b * 4 + lc) * LL + m;
  pmax[idx] = mx; psum[idx] = s;
}

__global__ __launch_bounds__(256) void col_stats_p2(
    const float* __restrict__ pmax, const float* __restrict__ psum,
    float* __restrict__ cmax, float* __restrict__ cinv)
{
  const int b = blockIdx.y;
  const int m = blockIdx.x * 256 + threadIdx.x;
  float M = -INFINITY;
#pragma unroll
  for (int i = 0; i < 4; ++i) M = fmaxf(M, pmax[(b * 4 + i) * LL + m]);
  float S = 0.f;
#pragma unroll
  for (int i = 0; i < 4; ++i) S += psum[(b * 4 + i) * LL + m] * __expf(pmax[(b * 4 + i) * LL + m] - M);
  cmax[(size_t)b * LL + m] = M;
  cinv[(size_t)b * LL + m] = 1.f / S;
}

// ---------------- P_alpha[m][l] (bf16, transposed) ----------------
__global__ __launch_bounds__(256) void palpha_kernel(
    const float* __restrict__ E, const float* __restrict__ mask1,
    const float* __restrict__ cmax, const float* __restrict__ cinv,
    unsigned short* __restrict__ Pa)
{
  __shared__ float T[64][65];
  const int b = blockIdx.z;
  const int l0 = blockIdx.y * 64, m0 = blockIdx.x * 64;
  const int tid = threadIdx.x;
  const int rr = tid >> 4, c4 = (tid & 15) * 4;
  const float4 cm = *(const float4*)(cmax + b * LL + m0 + c4);
  const float4 ci = *(const float4*)(cinv + b * LL + m0 + c4);
#pragma unroll
  for (int it = 0; it < 4; ++it) {
    const int lloc = rr + it * 16;
    const int l = l0 + lloc;
    const float mk = mask1[b * LL + l];
    const float4 ev = *(const float4*)(E + ((size_t)b * LL + l) * LL + m0 + c4);
    T[c4 + 0][lloc] = __expf(ev.x * mk - cm.x) * ci.x;
    T[c4 + 1][lloc] = __expf(ev.y * mk - cm.y) * ci.y;
    T[c4 + 2][lloc] = __expf(ev.z * mk - cm.z) * ci.z;
    T[c4 + 3][lloc] = __expf(ev.w * mk - cm.w) * ci.w;
  }
  __syncthreads();
#pragma unroll
  for (int it = 0; it < 4; ++it) {
    const int mloc = rr + it * 16;
    ushort4 o;
    o.x = f2bf(T[mloc][c4 + 0]);
    o.y = f2bf(T[mloc][c4 + 1]);
    o.z = f2bf(T[mloc][c4 + 2]);
    o.w = f2bf(T[mloc][c4 + 3]);
    *(ushort4*)(Pa + ((size_t)b * LL + m0 + mloc) * LL + l0 + c4) = o;
  }
}

// ---------------- s transpose+cast: S[b][l][0:600] fp32 -> St[b][0:640][l] bf16 ----------------
__global__ __launch_bounds__(256) void s_transpose(
    const float* __restrict__ S, unsigned short* __restrict__ St)
{
  __shared__ float T[64][65];
  const int b = blockIdx.z;
  const int l0 = blockIdx.y * 64, d0 = blockIdx.x * 64;
  const int tid = threadIdx.x;
  const int rr = tid >> 4, c4 = (tid & 15) * 4;
#pragma unroll
  for (int it = 0; it < 4; ++it) {
    const int lloc = rr + it * 16;
    const int l = l0 + lloc;
    float4 v = make_float4(0.f, 0.f, 0.f, 0.f);
    if (d0 + c4 < INP) v = *(const float4*)(S + ((size_t)b * LL + l) * INP + d0 + c4);
    T[c4 + 0][lloc] = v.x; T[c4 + 1][lloc] = v.y;
    T[c4 + 2][lloc] = v.z; T[c4 + 3][lloc] = v.w;
  }
  __syncthreads();
#pragma unroll
  for (int it = 0; it < 4; ++it) {
    const int dloc = rr + it * 16;
    ushort4 o;
    o.x = f2bf(T[dloc][c4 + 0]);
    o.y = f2bf(T[dloc][c4 + 1]);
    o.z = f2bf(T[dloc][c4 + 2]);
    o.w = f2bf(T[dloc][c4 + 3]);
    *(ushort4*)(St + ((size_t)b * DPAD + d0 + dloc) * LL + l0 + c4) = o;
  }
}

// ---------------- bf16 MFMA GEMM: Out[b][m][d] = (sum_k Ap[m][k]*Bt[d][k]) * scale[b][m] -------
__global__ __launch_bounds__(256) void attn_gemm_bf16(
    const unsigned short* __restrict__ Ap, const unsigned short* __restrict__ Bt,
    const float* __restrict__ scale, float* __restrict__ Out)
{
  __shared__ int4 sAB[2048];
  __shared__ float s_sc[128];
  const int b  = blockIdx.z;
  const int n0 = blockIdx.x * 128;
  const int m0 = blockIdx.y * 128;
  const int tid = threadIdx.x;
  const int lane = tid & 63;
  const int w = tid >> 6;
  const int wr = w >> 1, wc = w & 1;
  const int fr = lane & 15, kg = lane >> 4;

  const unsigned short* __restrict__ A  = Ap + (size_t)b * LL * LL;
  const unsigned short* __restrict__ Bp = Bt + (size_t)b * DPAD * LL;

  if (tid < 128) s_sc[tid] = scale[b * LL + m0 + tid];

  f32x4 acc[4][4];
#pragma unroll
  for (int mi = 0; mi < 4; ++mi)
#pragma unroll
    for (int ni = 0; ni < 4; ++ni)
      acc[mi][ni] = (f32x4){0.f, 0.f, 0.f, 0.f};

  for (int k0 = 0; k0 < LL; k0 += 64) {
    __syncthreads();
#pragma unroll
    for (int i = 0; i < 8; ++i) {
      const int s = w * 512 + i * 64 + lane;
      const int tens = s >> 10, rem = s & 1023, r = rem >> 3, kc = rem & 7;
      const int gc = kc ^ (r & 7);
      const unsigned short* src = tens ? (Bp + (size_t)(n0 + r) * LL + k0 + gc * 8)
                                       : (A  + (size_t)(m0 + r) * LL + k0 + gc * 8);
      gload16(src, (char*)sAB + ((size_t)(w * 512 + i * 64)) * 16);
    }
    __syncthreads();
#pragma unroll
    for (int kk = 0; kk < 2; ++kk) {
      short8v a[4], bf[4];
#pragma unroll
      for (int mi = 0; mi < 4; ++mi) {
        const int row = wr * 64 + mi * 16 + fr;
        a[mi] = *(const short8v*)&sAB[row * 8 + ((kk * 4 + kg) ^ (row & 7))];
      }
#pragma unroll
      for (int ni = 0; ni < 4; ++ni) {
        const int row = wc * 64 + ni * 16 + fr;
        bf[ni] = *(const short8v*)&sAB[1024 + row * 8 + ((kk * 4 + kg) ^ (row & 7))];
      }
#pragma unroll
      for (int mi = 0; mi < 4; ++mi)
#pragma unroll
        for (int ni = 0; ni < 4; ++ni)
          acc[mi][ni] = __builtin_amdgcn_mfma_f32_16x16x32_bf16(a[mi], bf[ni], acc[mi][ni], 0, 0, 0);
    }
  }

#pragma unroll
  for (int mi = 0; mi < 4; ++mi) {
#pragma unroll
    for (int ni = 0; ni < 4; ++ni) {
      const int col = n0 + wc * 64 + ni * 16 + fr;
      if (col < INP) {
#pragma unroll
        for (int r = 0; r < 4; ++r) {
          const int mrow = wr * 64 + mi * 16 + kg * 4 + r;
          Out[((size_t)b * LL + m0 + mrow) * INP + col] = acc[mi][ni][r] * s_sc[mrow];
        }
      }
    }
  }
}

// =================== fp32 fallback kernels (round-1 path, only if ws too small) ================
__device__ __forceinline__ void micro_8x8(const float (&sA)[KT][BM], const float (&sB)[KT][BN],
                                          float (&acc)[8][8], int tx, int ty)
{
#pragma unroll
  for (int kk = 0; kk < KT; ++kk) {
    float4 a0 = *(const float4*)&sA[kk][ty * 8];
    float4 a1 = *(const float4*)&sA[kk][ty * 8 + 4];
    float4 b0 = *(const float4*)&sB[kk][tx * 8];
    float4 b1 = *(const float4*)&sB[kk][tx * 8 + 4];
    float ar[8] = {a0.x, a0.y, a0.z, a0.w, a1.x, a1.y, a1.z, a1.w};
    float br[8] = {b0.x, b0.y, b0.z, b0.w, b1.x, b1.y, b1.z, b1.w};
#pragma unroll
    for (int i = 0; i < 8; ++i)
#pragma unroll
      for (int j = 0; j < 8; ++j)
        acc[i][j] = fmaf(ar[i], br[j], acc[i][j]);
  }
}

__global__ __launch_bounds__(256) void mlp_gemm(
    const float* __restrict__ A0, const float* __restrict__ A1,
    const float* __restrict__ W,  const float* __restrict__ bias,
    float* __restrict__ Out, int K)
{
  __shared__ __align__(16) float sA[KT][BM];
  __shared__ __align__(16) float sB[KT][BN];
  const int z = blockIdx.z;
  const float* __restrict__ A = z ? A1 : A0;
  float* __restrict__ out = Out + (size_t)z * RS * HID;
  const int m0 = blockIdx.x * BM;
  const int n0 = blockIdx.y * BN;
  const int tid = threadIdx.x;
  const int tx = tid & 15, ty = tid >> 4;
  const int am = tid & 127, akg = (tid >> 7) * 4;
  const int bn = (tid & 31) * 4, bkk = tid >> 5;

  float acc[8][8] = {};
  for (int k0 = 0; k0 < K; k0 += KT) {
    float4 av = *(const float4*)(A + (size_t)(m0 + am) * K + k0 + akg);
    sA[akg + 0][am] = av.x; sA[akg + 1][am] = av.y;
    sA[akg + 2][am] = av.z; sA[akg + 3][am] = av.w;
    const int gn = n0 + bn;
    float4 bv = make_float4(0.f, 0.f, 0.f, 0.f);
    if (gn < HID) bv = *(const float4*)(W + (size_t)(k0 + bkk) * HID + gn);
    *(float4*)&sB[bkk][bn] = bv;
    __syncthreads();
    micro_8x8(sA, sB, acc, tx, ty);
    __syncthreads();
  }
#pragma unroll
  for (int i = 0; i < 8; ++i) {
    const int m = m0 + ty * 8 + i;
#pragma unroll
    for (int j4 = 0; j4 < 8; j4 += 4) {
      const int n = n0 + tx * 8 + j4;
      if (n < HID) {
        float4 v;
        v.x = relu(acc[i][j4 + 0] + bias[n + 0]);
        v.y = relu(acc[i][j4 + 1] + bias[n + 1]);
        v.z = relu(acc[i][j4 + 2] + bias[n + 2]);
        v.w = relu(acc[i][j4 + 3] + bias[n + 3]);
        *(float4*)(out + (size_t)m * HID + n) = v;
      }
    }
  }
}

__global__ __launch_bounds__(256) void e_gemm(
    const float* __restrict__ H1, const float* __restrict__ H2, float* __restrict__ E)
{
  __shared__ __align__(16) float sA[KT][BM];
  __shared__ __align__(16) float sB[KT][BN];
  const int b = blockIdx.z;
  const float* __restrict__ A  = H1 + (size_t)b * LL * HID;
  const float* __restrict__ Bp = H2 + (size_t)b * LL * HID;
  float* __restrict__ e = E + (size_t)b * LL * LL;
  const int l0 = blockIdx.x * BM;
  const int m0 = blockIdx.y * BN;
  const int tid = threadIdx.x;
  const int tx = tid & 15, ty = tid >> 4;
  const int rr = tid & 127, kg = (tid >> 7) * 4;

  float acc[8][8] = {};
  for (int k0 = 0; k0 < HID; k0 += KT) {
    float4 av = *(const float4*)(A + (size_t)(l0 + rr) * HID + k0 + kg);
    sA[kg + 0][rr] = av.x; sA[kg + 1][rr] = av.y;
    sA[kg + 2][rr] = av.z; sA[kg + 3][rr] = av.w;
    float4 bv = *(const float4*)(Bp + (size_t)(m0 + rr) * HID + k0 + kg);
    sB[kg + 0][rr] = bv.x; sB[kg + 1][rr] = bv.y;
    sB[kg + 2][rr] = bv.z; sB[kg + 3][rr] = bv.w;
    __syncthreads();
    micro_8x8(sA, sB, acc, tx, ty);
    __syncthreads();
  }
#pragma unroll
  for (int i = 0; i < 8; ++i) {
    float* erow = e + (size_t)(l0 + ty * 8 + i) * LL + m0 + tx * 8;
    *(float4*)(erow)     = make_float4(acc[i][0], acc[i][1], acc[i][2], acc[i][3]);
    *(float4*)(erow + 4) = make_float4(acc[i][4], acc[i][5], acc[i][6], acc[i][7]);
  }
}

__global__ __launch_bounds__(256) void row_stats(
    const float* __restrict__ E, const float* __restrict__ mask2,
    float* __restrict__ rmax, float* __restrict__ rinv)
{
  const int wid = threadIdx.x >> 6, lane = threadIdx.x & 63;
  const int r = blockIdx.x * 4 + wid;
  const int b = r >> 10;
  const float* __restrict__ row = E + (size_t)r * LL;
  const float* __restrict__ m2 = mask2 + b * LL;
  float v[16];
  float mx = -INFINITY;
#pragma unroll
  for (int i = 0; i < 4; ++i) {
    const int m = lane * 4 + i * 256;
    float4 e4 = *(const float4*)(row + m);
    float4 k4 = *(const float4*)(m2 + m);
    v[i * 4 + 0] = e4.x * k4.x; v[i * 4 + 1] = e4.y * k4.y;
    v[i * 4 + 2] = e4.z * k4.z; v[i * 4 + 3] = e4.w * k4.w;
    mx = fmaxf(mx, fmaxf(fmaxf(v[i * 4], v[i * 4 + 1]), fmaxf(v[i * 4 + 2], v[i * 4 + 3])));
  }
#pragma unroll
  for (int off = 32; off; off >>= 1) mx = fmaxf(mx, __shfl_xor(mx, off));
  float s = 0.f;
#pragma unroll
  for (int i = 0; i < 16; ++i) s += __expf(v[i] - mx);
#pragma unroll
  for (int off = 32; off; off >>= 1) s += __shfl_xor(s, off);
  if (lane == 0) { rmax[r] = mx; rinv[r] = 1.f / s; }
}

__global__ __launch_bounds__(256) void alphas_gemm(
    const float* __restrict__ E, const float* __restrict__ S1,
    const float* __restrict__ mask1, const float* __restrict__ mask2,
    const float* __restrict__ cmax, const float* __restrict__ cinv,
    float* __restrict__ OutA)
{
  __shared__ __align__(16) float sA[KT][BM];
  __shared__ __align__(16) float sB[KT][BN];
  __shared__ __align__(16) float s_cm[BM], s_ci[BM], s_m2[BM];
  const int b = blockIdx.z;
  const float* __restrict__ e  = E  + (size_t)b * LL * LL;
  const float* __restrict__ s1 = S1 + (size_t)b * LL * INP;
  const int m0 = blockIdx.x * BM;
  const int d0 = blockIdx.y * BN;
  const int tid = threadIdx.x;
  const int tx = tid & 15, ty = tid >> 4;
  if (tid < BM) {
    s_cm[tid] = cmax[b * LL + m0 + tid];
    s_ci[tid] = cinv[b * LL + m0 + tid];
    s_m2[tid] = mask2[b * LL + m0 + tid];
  }
  __syncthreads();
  const int cc = (tid & 31) * 4, kk_ = tid >> 5;

  float acc[8][8] = {};
  for (int k0 = 0; k0 < LL; k0 += KT) {
    const int l = k0 + kk_;
    const float mk = mask1[b * LL + l];
    float4 ev = *(const float4*)(e + (size_t)l * LL + m0 + cc);
    float4 av;
    av.x = __expf(ev.x * mk - s_cm[cc + 0]) * s_ci[cc + 0];
    av.y = __expf(ev.y * mk - s_cm[cc + 1]) * s_ci[cc + 1];
    av.z = __expf(ev.z * mk - s_cm[cc + 2]) * s_ci[cc + 2];
    av.w = __expf(ev.w * mk - s_cm[cc + 3]) * s_ci[cc + 3];
    *(float4*)&sA[kk_][cc] = av;
    const int gd = d0 + cc;
    float4 bv = make_float4(0.f, 0.f, 0.f, 0.f);
    if (gd < INP) bv = *(const float4*)(s1 + (size_t)l * INP + gd);
    *(float4*)&sB[kk_][cc] = bv;
    __syncthreads();
    micro_8x8(sA, sB, acc, tx, ty);
    __syncthreads();
  }
#pragma unroll
  for (int i = 0; i < 8; ++i) {
    const int m = m0 + ty * 8 + i;
    const float mm = s_m2[ty * 8 + i];
    float* orow = OutA + ((size_t)b * LL + m) * INP;
#pragma unroll
    for (int j4 = 0; j4 < 8; j4 += 4) {
      const int d = d0 + tx * 8 + j4;
      if (d < INP) {
        *(float4*)(orow + d) = make_float4(acc[i][j4] * mm, acc[i][j4 + 1] * mm,
                                           acc[i][j4 + 2] * mm, acc[i][j4 + 3] * mm);
      }
    }
  }
}

__global__ __launch_bounds__(256) void betas_gemm(
    const float* __restrict__ E, const float* __restrict__ S2,
    const float* __restrict__ mask1, const float* __restrict__ mask2,
    const float* __restrict__ rmax, const float* __restrict__ rinv,
    float* __restrict__ OutB)
{
  __shared__ __align__(16) float sA[KT][BM];
  __shared__ __align__(16) float sB[KT][BN];
  __shared__ __align__(16) float s_rm[BM], s_ri[BM], s_m1[BM];
  const int b = blockIdx.z;
  const float* __restrict__ e  = E  + (size_t)b * LL * LL;
  const float* __restrict__ s2 = S2 + (size_t)b * LL * INP;
  const int l0 = blockIdx.x * BM;
  const int d0 = blockIdx.y * BN;
  const int tid = threadIdx.x;
  const int tx = tid & 15, ty = tid >> 4;
  if (tid < BM) {
    s_rm[tid] = rmax[b * LL + l0 + tid];
    s_ri[tid] = rinv[b * LL + l0 + tid];
    s_m1[tid] = mask1[b * LL + l0 + tid];
  }
  __syncthreads();
  const int al = tid & 127, akg = (tid >> 7) * 4;
  const int cc = (tid & 31) * 4, kk_ = tid >> 5;

  float acc[8][8] = {};
  for (int k0 = 0; k0 < LL; k0 += KT) {
    float4 ev = *(const float4*)(e + (size_t)(l0 + al) * LL + k0 + akg);
    float4 mk = *(const float4*)(mask2 + b * LL + k0 + akg);
    const float rm = s_rm[al], ri = s_ri[al];
    sA[akg + 0][al] = __expf(ev.x * mk.x - rm) * ri;
    sA[akg + 1][al] = __expf(ev.y * mk.y - rm) * ri;
    sA[akg + 2][al] = __expf(ev.z * mk.z - rm) * ri;
    sA[akg + 3][al] = __expf(ev.w * mk.w - rm) * ri;
    const int gd = d0 + cc;
    float4 bv = make_float4(0.f, 0.f, 0.f, 0.f);
    if (gd < INP) bv = *(const float4*)(s2 + (size_t)(k0 + kk_) * INP + gd);
    *(float4*)&sB[kk_][cc] = bv;
    __syncthreads();
    micro_8x8(sA, sB, acc, tx, ty);
    __syncthreads();
  }
#pragma unroll
  for (int i = 0; i < 8; ++i) {
    const int l = l0 + ty * 8 + i;
    const float mm = s_m1[ty * 8 + i];
    float* orow = OutB + ((size_t)b * LL + l) * INP;
#pragma unroll
    for (int j4 = 0; j4 < 8; j4 += 4) {
      const int d = d0 + tx * 8 + j4;
      if (d < INP) {
        *(float4*)(orow + d) = make_float4(acc[i][j4] * mm, acc[i][j4 + 1] * mm,
                                           acc[i][j4 + 2] * mm, acc[i][j4 + 3] * mm);
      }
    }
  }
}

} // namespace

extern "C" void kernel_launch(void* const* d_in, const int* in_sizes, int n_in,
                              void* d_out, int out_size, void* d_ws, size_t ws_size,
                              hipStream_t stream)
{
  const float* s1    = (const float*)d_in[0];
  const float* s2    = (const float*)d_in[1];
  const float* mask1 = (const float*)d_in[2];
  const float* mask2 = (const float*)d_in[3];
  const float* W1    = (const float*)d_in[4];
  const float* b1    = (const float*)d_in[5];
  const float* W2    = (const float*)d_in[6];
  const float* b2    = (const float*)d_in[7];

  char* ws = (char*)d_ws;
  float* outA = (float*)d_out;
  float* outB = outA + (size_t)BB * LL * INP;

  // -------- fast-path workspace layout (bytes), lifetime-packed (TOTAL unchanged vs r4) --------
  // sp_hi  [0,           83,886,080)   2*RS*640 bf16     dead after mlp1
  // sp_lo  [83,886,080, 167,772,160)                     dead after mlp1
  // hmid   [167,772,160,234,881,024)   hi|lo 2*RS*256    dead after mlp2
  // Wt1/2  [234,881,024,~235,798,528)                    dead after mlp2
  // h      [0,           67,108,864)   hi|lo 2*RS*256    dead after e     (overlays sp_hi)
  // stats  [67,108,864,  ~68.7M)                                          (dead sp_hi tail)
  // E      [104,857,600,239,075,328)   fp32 BB*LL*LL     dead after palpha
  // Pa     [0,           67,108,864)   bf16              (overlays h, after e)
  // s1t/s2t[104,857,600,188,743,680)   bf16              (overlays E, after palpha)
  // Pb     [239,075,328,306,184,192)   bf16
  const size_t off_splo = 83886080;
  const size_t off_hmid = 167772160;
  const size_t off_wt   = 234881024;
  const size_t off_E    = 104857600;
  const size_t off_Pb   = 239075328;
  const size_t TOTAL    = 306184192;

  if (ws_size >= TOTAL) {
    unsigned short* sp_hi = (unsigned short*)(ws + 0);
    unsigned short* sp_lo = (unsigned short*)(ws + off_splo);
    unsigned short* hmid_hi = (unsigned short*)(ws + off_hmid);
    unsigned short* hmid_lo = hmid_hi + (size_t)2 * RS * KP2;
    unsigned short* Wt1hi = (unsigned short*)(ws + off_wt);
    unsigned short* Wt1lo = Wt1hi + (size_t)256 * KP1;
    unsigned short* Wt2hi = Wt1lo + (size_t)256 * KP1;
    unsigned short* Wt2lo = Wt2hi + (size_t)256 * KP2;
    unsigned short* h_hi = (unsigned short*)(ws + 0);
    unsigned short* h_lo = h_hi + (size_t)2 * RS * KP2;
    float* E = (float*)(ws + off_E);
    unsigned short* Pb = (unsigned short*)(ws + off_Pb);
    unsigned short* Pa = (unsigned short*)(ws + 0);
    float* stats = (float*)(ws + 67108864);
    float* cmax = stats;
    float* cinv = cmax + RS;
    float* pmax = cinv + RS;
    float* psum = pmax + (size_t)BB * 4 * LL;
    unsigned short* s1t = (unsigned short*)(ws + off_E);
    unsigned short* s2t = s1t + (size_t)BB * DPAD * LL;

    // 1) prep: split weights and inputs
    wt_prep<<<dim3(3, 256), 256, 0, stream>>>(W1, Wt1hi, Wt1lo, INP, KP1);
    wt_prep<<<dim3(1, 256), 256, 0, stream>>>(W2, Wt2hi, Wt2lo, HID, KP2);
    presplit<<<dim3((2 * RS * 160) / 256), 256, 0, stream>>>(s1, s2, sp_hi, sp_lo);
    // 2) MLP layer 1: hmid = relu(s @ W1 + b1), split output
    splitmm2<true><<<dim3(RS / 128, 2, 2), 256, 0, stream>>>(
        sp_hi, sp_lo, (long)RS * KP1, KP1,
        Wt1hi, Wt1lo, 0, KP1, 10, b1,
        hmid_hi, hmid_lo, nullptr, KP2, (long)RS * KP2);
    // 3) MLP layer 2: h = relu(hmid @ W2 + b2), split output
    splitmm2<true><<<dim3(RS / 128, 2, 2), 256, 0, stream>>>(
        hmid_hi, hmid_lo, (long)RS * KP2, KP2,
        Wt2hi, Wt2lo, 0, KP2, 4, b2,
        h_hi, h_lo, nullptr, KP2, (long)RS * KP2);
    // 4) e = h1 @ h2^T
    splitmm2<false><<<dim3(8, 8, BB), 256, 0, stream>>>(
        h_hi, h_lo, (long)LL * KP2, KP2,
        h_hi + (size_t)RS * KP2, h_lo + (size_t)RS * KP2, (long)LL * KP2, KP2, 4, nullptr,
        nullptr, nullptr, E, LL, (long)LL * LL);
    // 5) softmax stats + P matrices
    row_stats_pbeta<<<dim3(RS / 4), 256, 0, stream>>>(E, mask2, Pb);
    col_stats_p1<<<dim3(4, 4, BB), 256, 0, stream>>>(E, mask1, pmax, psum);
    col_stats_p2<<<dim3(4, BB), 256, 0, stream>>>(pmax, psum, cmax, cinv);
    palpha_kernel<<<dim3(16, 16, BB), 256, 0, stream>>>(E, mask1, cmax, cinv, Pa);  // E dead
    // 6) s transposes (overlay E region)
    s_transpose<<<dim3(10, 16, BB), 256, 0, stream>>>(s1, s1t);
    s_transpose<<<dim3(10, 16, BB), 256, 0, stream>>>(s2, s2t);
    // 7) outputs
    attn_gemm_bf16<<<dim3(5, 8, BB), 256, 0, stream>>>(Pb, s2t, mask1, outB);
    attn_gemm_bf16<<<dim3(5, 8, BB), 256, 0, stream>>>(Pa, s1t, mask2, outA);
  } else {
    // -------- fallback: round-1 fp32 path (188 MB) --------
    float* h    = (float*)ws;
    float* hmid = h + (size_t)2 * RS * HID;
    float* E    = hmid;
    float* stats = hmid + (size_t)BB * LL * LL;
    float* rmax = stats;
    float* rinv = rmax + RS;
    float* cmax = rinv + RS;
    float* cinv = cmax + RS;
    float* pmax = cinv + RS;
    float* psum = pmax + (size_t)BB * 4 * LL;

    mlp_gemm<<<dim3(RS / BM, 2, 2), 256, 0, stream>>>(s1, s2, W1, b1, hmid, INP);
    mlp_gemm<<<dim3(RS / BM, 2, 2), 256, 0, stream>>>(hmid, hmid + (size_t)RS * HID, W2, b2, h, HID);
    e_gemm<<<dim3(LL / BM, LL / BN, BB), 256, 0, stream>>>(h, h + (size_t)RS * HID, E);
    row_stats<<<dim3(RS / 4), 256, 0, stream>>>(E, mask2, rmax, rinv);
    col_stats_p1<<<dim3(4, 4, BB), 256, 0, stream>>>(E, mask1, pmax, psum);
    col_stats_p2<<<dim3(4, BB), 256, 0, stream>>>(pmax, psum, cmax, cinv);
    alphas_gemm<<<dim3(LL / BM, (INP + BN - 1) / BN, BB), 256, 0, stream>>>(
        E, s1, mask1, mask2, cmax, cinv, outA);
    betas_gemm<<<dim3(LL / BM, (INP + BN - 1) / BN, BB), 256, 0, stream>>>(
        E, s2, mask1, mask2, rmax, rinv, outB);
  }

  (void)in_sizes; (void)n_in; (void)out_size;
}

// Round 7
// 866.547 us; speedup vs baseline: 1.0706x; 1.0706x over previous
//
#include <hip/hip_runtime.h>
#include <math.h>

namespace {

constexpr int BB  = 32;    // batch
constexpr int LL  = 1024;  // sequence length
constexpr int INP = 600;
constexpr int HID = 200;
constexpr int RS  = BB * LL;   // 32768 rows per stream
constexpr int DPAD = 640;      // padded d-dim for bf16 transposed s
constexpr int KP1 = 640;       // padded K for layer1 (INP=600 -> 640)
constexpr int KP2 = 256;       // padded K for layer2 / e (HID=200 -> 256)

constexpr int BM = 128, BN = 128, KT = 8;   // (fallback path tiles)

typedef __attribute__((ext_vector_type(8))) short short8v;           // bf16x8 fragment
typedef __attribute__((ext_vector_type(4))) float f32x4;

__device__ __forceinline__ float relu(float x) { return fmaxf(x, 0.f); }

__device__ __forceinline__ unsigned short f2bf(float x) {
  union { float f; unsigned int u; } v; v.f = x;
  unsigned int r = v.u + 0x7FFFu + ((v.u >> 16) & 1u);   // RNE
  return (unsigned short)(r >> 16);
}
__device__ __forceinline__ float bf2f(unsigned short h) {
  union { unsigned int u; float f; } v; v.u = ((unsigned int)h) << 16;
  return v.f;
}

// async global->LDS, 16B per lane; LDS dest = wave-uniform base + lane*16
__device__ __forceinline__ void gload16(const void* g, void* l) {
  __builtin_amdgcn_global_load_lds((const __attribute__((address_space(1))) void*)g,
                                   (__attribute__((address_space(3))) void*)l, 16, 0, 0);
}

// ============ presplit: s[2][RS][600] fp32 -> sp_hi/lo[2][RS][640] bf16, zero-padded ============
__global__ __launch_bounds__(256) void presplit(
    const float* __restrict__ S1, const float* __restrict__ S2,
    unsigned short* __restrict__ Hi, unsigned short* __restrict__ Lo)
{
  const long idx = (long)blockIdx.x * 256 + threadIdx.x;   // one 4-col quad each
  const long row = idx / 160;
  const int  c4  = (int)(idx - row * 160) * 4;
  const float* __restrict__ src = (row < RS) ? (S1 + row * (size_t)INP)
                                             : (S2 + (row - RS) * (size_t)INP);
  float4 v = make_float4(0.f, 0.f, 0.f, 0.f);
  if (c4 < INP) v = *(const float4*)(src + c4);
  ushort4 h4, l4;
  h4.x = f2bf(v.x); l4.x = f2bf(v.x - bf2f(h4.x));
  h4.y = f2bf(v.y); l4.y = f2bf(v.y - bf2f(h4.y));
  h4.z = f2bf(v.z); l4.z = f2bf(v.z - bf2f(h4.z));
  h4.w = f2bf(v.w); l4.w = f2bf(v.w - bf2f(h4.w));
  *(ushort4*)(Hi + row * (size_t)KP1 + c4) = h4;
  *(ushort4*)(Lo + row * (size_t)KP1 + c4) = l4;
}

// ============ W transpose + split prep: W[K][200] fp32 -> Wt_hi/lo[256][KP] bf16, zero-pad ======
__global__ __launch_bounds__(256) void wt_prep(
    const float* __restrict__ W, unsigned short* __restrict__ Whi, unsigned short* __restrict__ Wlo,
    int K, int KP)
{
  const int k = blockIdx.x * 256 + threadIdx.x;
  const int n = blockIdx.y;              // 0..255 (rows >=200 zero)
  if (k >= KP) return;
  float v = (k < K && n < HID) ? W[(size_t)k * HID + n] : 0.f;
  unsigned short hi = f2bf(v);
  unsigned short lo = f2bf(v - bf2f(hi));
  Whi[(size_t)n * KP + k] = hi;
  Wlo[(size_t)n * KP + k] = lo;
}

// ============ split-bf16 MFMA GEMM, ALL operands pre-split, pure global_load_lds staging ========
// Tile 128x128, 4 waves (2x2), BK=64. LDS: 4 planes of 1024 int4 slots
// (Ahi | Alo | Bhi | Blo), slot = row*8 + (chunk ^ (row&7)); wave w DMAs plane w.
// SPLIT_OUT=true : Out = split(relu(acc+bias)) -> bf16 hi/lo, zeros for gn>=HID. 3D grid.
// SPLIT_OUT=false: OutF = acc (fp32, no guard). 1D grid of 2048 blocks, XCD-swizzled so each
//                  XCD owns 4 contiguous batches (per-batch panels stay L2-resident).
template <bool SPLIT_OUT>
__global__ __launch_bounds__(256) void splitmm2(
    const unsigned short* __restrict__ Ahi, const unsigned short* __restrict__ Alo,
    long aZ, int lda,
    const unsigned short* __restrict__ Bhi, const unsigned short* __restrict__ Blo,
    long bZ, int ldb,
    int ksteps, const float* __restrict__ bias,
    unsigned short* __restrict__ OutHi, unsigned short* __restrict__ OutLo,
    float* __restrict__ OutF, int ldo, long oZ)
{
  __shared__ int4 sL[4096];
  int z, m0, n0;
  if (SPLIT_OUT) {
    z = blockIdx.z; m0 = blockIdx.x * 128; n0 = blockIdx.y * 128;
  } else {
    // 2048 blocks = 8 XCDs x 256; XCD j gets wid range [256j,256j+256) = batches 4j..4j+3
    const int bid = blockIdx.x;
    const int wid = (bid & 7) * 256 + (bid >> 3);
    z = wid >> 6;
    const int rem = wid & 63;
    m0 = (rem & 7) * 128;
    n0 = (rem >> 3) * 128;
  }
  const int tid = threadIdx.x, lane = tid & 63, w = tid >> 6;
  const int wr = w >> 1, wc = w & 1, fr = lane & 15, kg = lane >> 4;

  // wave-uniform staging plane
  const unsigned short* __restrict__ wbase =
      (w == 0) ? (Ahi + (size_t)z * aZ) :
      (w == 1) ? (Alo + (size_t)z * aZ) :
      (w == 2) ? (Bhi + (size_t)z * bZ) :
                 (Blo + (size_t)z * bZ);
  const int wrow0 = (w < 2) ? m0 : n0;
  const int wld   = (w < 2) ? lda : ldb;

  f32x4 acc[4][4];
#pragma unroll
  for (int mi = 0; mi < 4; ++mi)
#pragma unroll
    for (int ni = 0; ni < 4; ++ni) acc[mi][ni] = (f32x4){0.f, 0.f, 0.f, 0.f};

  for (int ks = 0; ks < ksteps; ++ks) {
    const int k0 = ks * 64;
    __syncthreads();
#pragma unroll
    for (int i = 0; i < 16; ++i) {
      const int s = w * 1024 + i * 64 + lane;
      const int rem = s & 1023, r = rem >> 3, kc = rem & 7;
      const int gc = kc ^ (r & 7);
      gload16(wbase + (size_t)(wrow0 + r) * wld + k0 + gc * 8,
              (char*)sL + (size_t)s * 16);
    }
    __syncthreads();
#pragma unroll
    for (int kk = 0; kk < 2; ++kk) {
      short8v ah[4], al[4], bh[4], bl[4];
#pragma unroll
      for (int mi = 0; mi < 4; ++mi) {
        const int row = wr * 64 + mi * 16 + fr;
        const int idx = row * 8 + ((kk * 4 + kg) ^ (row & 7));
        ah[mi] = *(const short8v*)&sL[idx];
        al[mi] = *(const short8v*)&sL[1024 + idx];
      }
#pragma unroll
      for (int ni = 0; ni < 4; ++ni) {
        const int row = wc * 64 + ni * 16 + fr;
        const int idx = row * 8 + ((kk * 4 + kg) ^ (row & 7));
        bh[ni] = *(const short8v*)&sL[2048 + idx];
        bl[ni] = *(const short8v*)&sL[3072 + idx];
      }
#pragma unroll
      for (int mi = 0; mi < 4; ++mi)
#pragma unroll
        for (int ni = 0; ni < 4; ++ni) {
          acc[mi][ni] = __builtin_amdgcn_mfma_f32_16x16x32_bf16(ah[mi], bh[ni], acc[mi][ni], 0, 0, 0);
          acc[mi][ni] = __builtin_amdgcn_mfma_f32_16x16x32_bf16(ah[mi], bl[ni], acc[mi][ni], 0, 0, 0);
          acc[mi][ni] = __builtin_amdgcn_mfma_f32_16x16x32_bf16(al[mi], bh[ni], acc[mi][ni], 0, 0, 0);
        }
    }
  }
  // ---- epilogue (C/D: col = lane&15, row = (lane>>4)*4 + reg)
#pragma unroll
  for (int ni = 0; ni < 4; ++ni) {
    const int gn = n0 + wc * 64 + ni * 16 + fr;
    if (SPLIT_OUT) {
      const bool valid = gn < HID;
      const float bs = valid ? bias[gn] : 0.f;
#pragma unroll
      for (int mi = 0; mi < 4; ++mi) {
#pragma unroll
        for (int r = 0; r < 4; ++r) {
          const int gm = m0 + wr * 64 + mi * 16 + kg * 4 + r;
          unsigned short hi = 0, lo = 0;
          if (valid) {
            float v = relu(acc[mi][ni][r] + bs);
            hi = f2bf(v);
            lo = f2bf(v - bf2f(hi));
          }
          OutHi[(size_t)z * oZ + (size_t)gm * ldo + gn] = hi;
          OutLo[(size_t)z * oZ + (size_t)gm * ldo + gn] = lo;
        }
      }
    } else {
#pragma unroll
      for (int mi = 0; mi < 4; ++mi) {
#pragma unroll
        for (int r = 0; r < 4; ++r) {
          const int gm = m0 + wr * 64 + mi * 16 + kg * 4 + r;
          OutF[(size_t)z * oZ + (size_t)gm * ldo + gn] = acc[mi][ni][r];
        }
      }
    }
  }
}

// ---------------- fused row stats + P_beta: one E read, bf16 P out ----------------
__global__ __launch_bounds__(256) void row_stats_pbeta(
    const float* __restrict__ E, const float* __restrict__ mask2,
    unsigned short* __restrict__ Pb)
{
  const int wid = threadIdx.x >> 6, lane = threadIdx.x & 63;
  const int r = blockIdx.x * 4 + wid;
  const int b = r >> 10;
  const float* __restrict__ row = E + (size_t)r * LL;
  const float* __restrict__ m2 = mask2 + b * LL;
  float v[16];
  float mx = -INFINITY;
#pragma unroll
  for (int i = 0; i < 4; ++i) {
    const int m = lane * 4 + i * 256;
    float4 e4 = *(const float4*)(row + m);
    float4 k4 = *(const float4*)(m2 + m);
    v[i * 4 + 0] = e4.x * k4.x; v[i * 4 + 1] = e4.y * k4.y;
    v[i * 4 + 2] = e4.z * k4.z; v[i * 4 + 3] = e4.w * k4.w;
    mx = fmaxf(mx, fmaxf(fmaxf(v[i * 4], v[i * 4 + 1]), fmaxf(v[i * 4 + 2], v[i * 4 + 3])));
  }
#pragma unroll
  for (int off = 32; off; off >>= 1) mx = fmaxf(mx, __shfl_xor(mx, off));
  float s = 0.f;
#pragma unroll
  for (int i = 0; i < 16; ++i) s += __expf(v[i] - mx);
#pragma unroll
  for (int off = 32; off; off >>= 1) s += __shfl_xor(s, off);
  const float ri = 1.f / s;
#pragma unroll
  for (int i = 0; i < 4; ++i) {
    const int m = lane * 4 + i * 256;
    ushort4 o;
    o.x = f2bf(__expf(v[i * 4 + 0] - mx) * ri);
    o.y = f2bf(__expf(v[i * 4 + 1] - mx) * ri);
    o.z = f2bf(__expf(v[i * 4 + 2] - mx) * ri);
    o.w = f2bf(__expf(v[i * 4 + 3] - mx) * ri);
    *(ushort4*)(Pb + (size_t)r * LL + m) = o;
  }
}

// ---------------- column stats (alpha softmax over l), two-pass ----------------
__global__ __launch_bounds__(256) void col_stats_p1(
    const float* __restrict__ E, const float* __restrict__ mask1,
    float* __restrict__ pmax, float* __restrict__ psum)
{
  const int b = blockIdx.z, lc = blockIdx.y;
  const int m = blockIdx.x * 256 + threadIdx.x;
  const float* __restrict__ e = E + (size_t)b * LL * LL;
  const float* __restrict__ m1 = mask1 + b * LL;
  float mx = -INFINITY, s = 0.f;
#pragma unroll 4
  for (int l = lc * 256; l < lc * 256 + 256; ++l) {
    const float v = e[(size_t)l * LL + m] * m1[l];
    if (v > mx) { s = s * __expf(mx - v) + 1.f; mx = v; }
    else        { s += __expf(v - mx); }
  }
  const int idx = (b * 4 + lc) * LL + m;
  pmax[idx] = mx; psum[idx] = s;
}

__global__ __launch_bounds__(256) void col_stats_p2(
    const float* __restrict__ pmax, const float* __restrict__ psum,
    float* __restrict__ cmax, float* __restrict__ cinv)
{
  const int b = blockIdx.y;
  const int m = blockIdx.x * 256 + threadIdx.x;
  float M = -INFINITY;
#pragma unroll
  for (int i = 0; i < 4; ++i) M = fmaxf(M, pmax[(b * 4 + i) * LL + m]);
  float S = 0.f;
#pragma unroll
  for (int i = 0; i < 4; ++i) S += psum[(b * 4 + i) * LL + m] * __expf(pmax[(b * 4 + i) * LL + m] - M);
  cmax[(size_t)b * LL + m] = M;
  cinv[(size_t)b * LL + m] = 1.f / S;
}

// ---------------- P_alpha[m][l] (bf16, transposed) ----------------
__global__ __launch_bounds__(256) void palpha_kernel(
    const float* __restrict__ E, const float* __restrict__ mask1,
    const float* __restrict__ cmax, const float* __restrict__ cinv,
    unsigned short* __restrict__ Pa)
{
  __shared__ float T[64][65];
  const int b = blockIdx.z;
  const int l0 = blockIdx.y * 64, m0 = blockIdx.x * 64;
  const int tid = threadIdx.x;
  const int rr = tid >> 4, c4 = (tid & 15) * 4;
  const float4 cm = *(const float4*)(cmax + b * LL + m0 + c4);
  const float4 ci = *(const float4*)(cinv + b * LL + m0 + c4);
#pragma unroll
  for (int it = 0; it < 4; ++it) {
    const int lloc = rr + it * 16;
    const int l = l0 + lloc;
    const float mk = mask1[b * LL + l];
    const float4 ev = *(const float4*)(E + ((size_t)b * LL + l) * LL + m0 + c4);
    T[c4 + 0][lloc] = __expf(ev.x * mk - cm.x) * ci.x;
    T[c4 + 1][lloc] = __expf(ev.y * mk - cm.y) * ci.y;
    T[c4 + 2][lloc] = __expf(ev.z * mk - cm.z) * ci.z;
    T[c4 + 3][lloc] = __expf(ev.w * mk - cm.w) * ci.w;
  }
  __syncthreads();
#pragma unroll
  for (int it = 0; it < 4; ++it) {
    const int mloc = rr + it * 16;
    ushort4 o;
    o.x = f2bf(T[mloc][c4 + 0]);
    o.y = f2bf(T[mloc][c4 + 1]);
    o.z = f2bf(T[mloc][c4 + 2]);
    o.w = f2bf(T[mloc][c4 + 3]);
    *(ushort4*)(Pa + ((size_t)b * LL + m0 + mloc) * LL + l0 + c4) = o;
  }
}

// ---------------- s transpose+cast: S[b][l][0:600] fp32 -> St[b][0:640][l] bf16 ----------------
__global__ __launch_bounds__(256) void s_transpose(
    const float* __restrict__ S, unsigned short* __restrict__ St)
{
  __shared__ float T[64][65];
  const int b = blockIdx.z;
  const int l0 = blockIdx.y * 64, d0 = blockIdx.x * 64;
  const int tid = threadIdx.x;
  const int rr = tid >> 4, c4 = (tid & 15) * 4;
#pragma unroll
  for (int it = 0; it < 4; ++it) {
    const int lloc = rr + it * 16;
    const int l = l0 + lloc;
    float4 v = make_float4(0.f, 0.f, 0.f, 0.f);
    if (d0 + c4 < INP) v = *(const float4*)(S + ((size_t)b * LL + l) * INP + d0 + c4);
    T[c4 + 0][lloc] = v.x; T[c4 + 1][lloc] = v.y;
    T[c4 + 2][lloc] = v.z; T[c4 + 3][lloc] = v.w;
  }
  __syncthreads();
#pragma unroll
  for (int it = 0; it < 4; ++it) {
    const int dloc = rr + it * 16;
    ushort4 o;
    o.x = f2bf(T[dloc][c4 + 0]);
    o.y = f2bf(T[dloc][c4 + 1]);
    o.z = f2bf(T[dloc][c4 + 2]);
    o.w = f2bf(T[dloc][c4 + 3]);
    *(ushort4*)(St + ((size_t)b * DPAD + d0 + dloc) * LL + l0 + c4) = o;
  }
}

// ---------------- bf16 MFMA GEMM: Out[b][m][d] = (sum_k Ap[m][k]*Bt[d][k]) * scale[b][m] -------
// 1D grid 1280 blocks, XCD-swizzled: XCD j owns batches 4j..4j+3, so each batch's
// A panel (2 MB) + B panel (1.25 MB) stay resident in that XCD's 4 MB L2.
__global__ __launch_bounds__(256) void attn_gemm_bf16(
    const unsigned short* __restrict__ Ap, const unsigned short* __restrict__ Bt,
    const float* __restrict__ scale, float* __restrict__ Out)
{
  __shared__ int4 sAB[2048];
  __shared__ float s_sc[128];
  const int bid = blockIdx.x;
  const int wid = (bid & 7) * 160 + (bid >> 3);   // bijective: 1280 = 8*160
  const int b = wid / 40;
  const int rem = wid - b * 40;
  const int n0 = (rem % 5) * 128;
  const int m0 = (rem / 5) * 128;
  const int tid = threadIdx.x;
  const int lane = tid & 63;
  const int w = tid >> 6;
  const int wr = w >> 1, wc = w & 1;
  const int fr = lane & 15, kg = lane >> 4;

  const unsigned short* __restrict__ A  = Ap + (size_t)b * LL * LL;
  const unsigned short* __restrict__ Bp = Bt + (size_t)b * DPAD * LL;

  if (tid < 128) s_sc[tid] = scale[b * LL + m0 + tid];

  f32x4 acc[4][4];
#pragma unroll
  for (int mi = 0; mi < 4; ++mi)
#pragma unroll
    for (int ni = 0; ni < 4; ++ni)
      acc[mi][ni] = (f32x4){0.f, 0.f, 0.f, 0.f};

  for (int k0 = 0; k0 < LL; k0 += 64) {
    __syncthreads();
#pragma unroll
    for (int i = 0; i < 8; ++i) {
      const int s = w * 512 + i * 64 + lane;
      const int tens = s >> 10, rem2 = s & 1023, r = rem2 >> 3, kc = rem2 & 7;
      const int gc = kc ^ (r & 7);
      const unsigned short* src = tens ? (Bp + (size_t)(n0 + r) * LL + k0 + gc * 8)
                                       : (A  + (size_t)(m0 + r) * LL + k0 + gc * 8);
      gload16(src, (char*)sAB + ((size_t)(w * 512 + i * 64)) * 16);
    }
    __syncthreads();
#pragma unroll
    for (int kk = 0; kk < 2; ++kk) {
      short8v a[4], bf[4];
#pragma unroll
      for (int mi = 0; mi < 4; ++mi) {
        const int row = wr * 64 + mi * 16 + fr;
        a[mi] = *(const short8v*)&sAB[row * 8 + ((kk * 4 + kg) ^ (row & 7))];
      }
#pragma unroll
      for (int ni = 0; ni < 4; ++ni) {
        const int row = wc * 64 + ni * 16 + fr;
        bf[ni] = *(const short8v*)&sAB[1024 + row * 8 + ((kk * 4 + kg) ^ (row & 7))];
      }
#pragma unroll
      for (int mi = 0; mi < 4; ++mi)
#pragma unroll
        for (int ni = 0; ni < 4; ++ni)
          acc[mi][ni] = __builtin_amdgcn_mfma_f32_16x16x32_bf16(a[mi], bf[ni], acc[mi][ni], 0, 0, 0);
    }
  }

#pragma unroll
  for (int mi = 0; mi < 4; ++mi) {
#pragma unroll
    for (int ni = 0; ni < 4; ++ni) {
      const int col = n0 + wc * 64 + ni * 16 + fr;
      if (col < INP) {
#pragma unroll
        for (int r = 0; r < 4; ++r) {
          const int mrow = wr * 64 + mi * 16 + kg * 4 + r;
          Out[((size_t)b * LL + m0 + mrow) * INP + col] = acc[mi][ni][r] * s_sc[mrow];
        }
      }
    }
  }
}

// =================== fp32 fallback kernels (round-1 path, only if ws too small) ================
__device__ __forceinline__ void micro_8x8(const float (&sA)[KT][BM], const float (&sB)[KT][BN],
                                          float (&acc)[8][8], int tx, int ty)
{
#pragma unroll
  for (int kk = 0; kk < KT; ++kk) {
    float4 a0 = *(const float4*)&sA[kk][ty * 8];
    float4 a1 = *(const float4*)&sA[kk][ty * 8 + 4];
    float4 b0 = *(const float4*)&sB[kk][tx * 8];
    float4 b1 = *(const float4*)&sB[kk][tx * 8 + 4];
    float ar[8] = {a0.x, a0.y, a0.z, a0.w, a1.x, a1.y, a1.z, a1.w};
    float br[8] = {b0.x, b0.y, b0.z, b0.w, b1.x, b1.y, b1.z, b1.w};
#pragma unroll
    for (int i = 0; i < 8; ++i)
#pragma unroll
      for (int j = 0; j < 8; ++j)
        acc[i][j] = fmaf(ar[i], br[j], acc[i][j]);
  }
}

__global__ __launch_bounds__(256) void mlp_gemm(
    const float* __restrict__ A0, const float* __restrict__ A1,
    const float* __restrict__ W,  const float* __restrict__ bias,
    float* __restrict__ Out, int K)
{
  __shared__ __align__(16) float sA[KT][BM];
  __shared__ __align__(16) float sB[KT][BN];
  const int z = blockIdx.z;
  const float* __restrict__ A = z ? A1 : A0;
  float* __restrict__ out = Out + (size_t)z * RS * HID;
  const int m0 = blockIdx.x * BM;
  const int n0 = blockIdx.y * BN;
  const int tid = threadIdx.x;
  const int tx = tid & 15, ty = tid >> 4;
  const int am = tid & 127, akg = (tid >> 7) * 4;
  const int bn = (tid & 31) * 4, bkk = tid >> 5;

  float acc[8][8] = {};
  for (int k0 = 0; k0 < K; k0 += KT) {
    float4 av = *(const float4*)(A + (size_t)(m0 + am) * K + k0 + akg);
    sA[akg + 0][am] = av.x; sA[akg + 1][am] = av.y;
    sA[akg + 2][am] = av.z; sA[akg + 3][am] = av.w;
    const int gn = n0 + bn;
    float4 bv = make_float4(0.f, 0.f, 0.f, 0.f);
    if (gn < HID) bv = *(const float4*)(W + (size_t)(k0 + bkk) * HID + gn);
    *(float4*)&sB[bkk][bn] = bv;
    __syncthreads();
    micro_8x8(sA, sB, acc, tx, ty);
    __syncthreads();
  }
#pragma unroll
  for (int i = 0; i < 8; ++i) {
    const int m = m0 + ty * 8 + i;
#pragma unroll
    for (int j4 = 0; j4 < 8; j4 += 4) {
      const int n = n0 + tx * 8 + j4;
      if (n < HID) {
        float4 v;
        v.x = relu(acc[i][j4 + 0] + bias[n + 0]);
        v.y = relu(acc[i][j4 + 1] + bias[n + 1]);
        v.z = relu(acc[i][j4 + 2] + bias[n + 2]);
        v.w = relu(acc[i][j4 + 3] + bias[n + 3]);
        *(float4*)(out + (size_t)m * HID + n) = v;
      }
    }
  }
}

__global__ __launch_bounds__(256) void e_gemm(
    const float* __restrict__ H1, const float* __restrict__ H2, float* __restrict__ E)
{
  __shared__ __align__(16) float sA[KT][BM];
  __shared__ __align__(16) float sB[KT][BN];
  const int b = blockIdx.z;
  const float* __restrict__ A  = H1 + (size_t)b * LL * HID;
  const float* __restrict__ Bp = H2 + (size_t)b * LL * HID;
  float* __restrict__ e = E + (size_t)b * LL * LL;
  const int l0 = blockIdx.x * BM;
  const int m0 = blockIdx.y * BN;
  const int tid = threadIdx.x;
  const int tx = tid & 15, ty = tid >> 4;
  const int rr = tid & 127, kg = (tid >> 7) * 4;

  float acc[8][8] = {};
  for (int k0 = 0; k0 < HID; k0 += KT) {
    float4 av = *(const float4*)(A + (size_t)(l0 + rr) * HID + k0 + kg);
    sA[kg + 0][rr] = av.x; sA[kg + 1][rr] = av.y;
    sA[kg + 2][rr] = av.z; sA[kg + 3][rr] = av.w;
    float4 bv = *(const float4*)(Bp + (size_t)(m0 + rr) * HID + k0 + kg);
    sB[kg + 0][rr] = bv.x; sB[kg + 1][rr] = bv.y;
    sB[kg + 2][rr] = bv.z; sB[kg + 3][rr] = bv.w;
    __syncthreads();
    micro_8x8(sA, sB, acc, tx, ty);
    __syncthreads();
  }
#pragma unroll
  for (int i = 0; i < 8; ++i) {
    float* erow = e + (size_t)(l0 + ty * 8 + i) * LL + m0 + tx * 8;
    *(float4*)(erow)     = make_float4(acc[i][0], acc[i][1], acc[i][2], acc[i][3]);
    *(float4*)(erow + 4) = make_float4(acc[i][4], acc[i][5], acc[i][6], acc[i][7]);
  }
}

__global__ __launch_bounds__(256) void row_stats(
    const float* __restrict__ E, const float* __restrict__ mask2,
    float* __restrict__ rmax, float* __restrict__ rinv)
{
  const int wid = threadIdx.x >> 6, lane = threadIdx.x & 63;
  const int r = blockIdx.x * 4 + wid;
  const int b = r >> 10;
  const float* __restrict__ row = E + (size_t)r * LL;
  const float* __restrict__ m2 = mask2 + b * LL;
  float v[16];
  float mx = -INFINITY;
#pragma unroll
  for (int i = 0; i < 4; ++i) {
    const int m = lane * 4 + i * 256;
    float4 e4 = *(const float4*)(row + m);
    float4 k4 = *(const float4*)(m2 + m);
    v[i * 4 + 0] = e4.x * k4.x; v[i * 4 + 1] = e4.y * k4.y;
    v[i * 4 + 2] = e4.z * k4.z; v[i * 4 + 3] = e4.w * k4.w;
    mx = fmaxf(mx, fmaxf(fmaxf(v[i * 4], v[i * 4 + 1]), fmaxf(v[i * 4 + 2], v[i * 4 + 3])));
  }
#pragma unroll
  for (int off = 32; off; off >>= 1) mx = fmaxf(mx, __shfl_xor(mx, off));
  float s = 0.f;
#pragma unroll
  for (int i = 0; i < 16; ++i) s += __expf(v[i] - mx);
#pragma unroll
  for (int off = 32; off; off >>= 1) s += __shfl_xor(s, off);
  if (lane == 0) { rmax[r] = mx; rinv[r] = 1.f / s; }
}

__global__ __launch_bounds__(256) void alphas_gemm(
    const float* __restrict__ E, const float* __restrict__ S1,
    const float* __restrict__ mask1, const float* __restrict__ mask2,
    const float* __restrict__ cmax, const float* __restrict__ cinv,
    float* __restrict__ OutA)
{
  __shared__ __align__(16) float sA[KT][BM];
  __shared__ __align__(16) float sB[KT][BN];
  __shared__ __align__(16) float s_cm[BM], s_ci[BM], s_m2[BM];
  const int b = blockIdx.z;
  const float* __restrict__ e  = E  + (size_t)b * LL * LL;
  const float* __restrict__ s1 = S1 + (size_t)b * LL * INP;
  const int m0 = blockIdx.x * BM;
  const int d0 = blockIdx.y * BN;
  const int tid = threadIdx.x;
  const int tx = tid & 15, ty = tid >> 4;
  if (tid < BM) {
    s_cm[tid] = cmax[b * LL + m0 + tid];
    s_ci[tid] = cinv[b * LL + m0 + tid];
    s_m2[tid] = mask2[b * LL + m0 + tid];
  }
  __syncthreads();
  const int cc = (tid & 31) * 4, kk_ = tid >> 5;

  float acc[8][8] = {};
  for (int k0 = 0; k0 < LL; k0 += KT) {
    const int l = k0 + kk_;
    const float mk = mask1[b * LL + l];
    float4 ev = *(const float4*)(e + (size_t)l * LL + m0 + cc);
    float4 av;
    av.x = __expf(ev.x * mk - s_cm[cc + 0]) * s_ci[cc + 0];
    av.y = __expf(ev.y * mk - s_cm[cc + 1]) * s_ci[cc + 1];
    av.z = __expf(ev.z * mk - s_cm[cc + 2]) * s_ci[cc + 2];
    av.w = __expf(ev.w * mk - s_cm[cc + 3]) * s_ci[cc + 3];
    *(float4*)&sA[kk_][cc] = av;
    const int gd = d0 + cc;
    float4 bv = make_float4(0.f, 0.f, 0.f, 0.f);
    if (gd < INP) bv = *(const float4*)(s1 + (size_t)l * INP + gd);
    *(float4*)&sB[kk_][cc] = bv;
    __syncthreads();
    micro_8x8(sA, sB, acc, tx, ty);
    __syncthreads();
  }
#pragma unroll
  for (int i = 0; i < 8; ++i) {
    const int m = m0 + ty * 8 + i;
    const float mm = s_m2[ty * 8 + i];
    float* orow = OutA + ((size_t)b * LL + m) * INP;
#pragma unroll
    for (int j4 = 0; j4 < 8; j4 += 4) {
      const int d = d0 + tx * 8 + j4;
      if (d < INP) {
        *(float4*)(orow + d) = make_float4(acc[i][j4] * mm, acc[i][j4 + 1] * mm,
                                           acc[i][j4 + 2] * mm, acc[i][j4 + 3] * mm);
      }
    }
  }
}

__global__ __launch_bounds__(256) void betas_gemm(
    const float* __restrict__ E, const float* __restrict__ S2,
    const float* __restrict__ mask1, const float* __restrict__ mask2,
    const float* __restrict__ rmax, const float* __restrict__ rinv,
    float* __restrict__ OutB)
{
  __shared__ __align__(16) float sA[KT][BM];
  __shared__ __align__(16) float sB[KT][BN];
  __shared__ __align__(16) float s_rm[BM], s_ri[BM], s_m1[BM];
  const int b = blockIdx.z;
  const float* __restrict__ e  = E  + (size_t)b * LL * LL;
  const float* __restrict__ s2 = S2 + (size_t)b * LL * INP;
  const int l0 = blockIdx.x * BM;
  const int d0 = blockIdx.y * BN;
  const int tid = threadIdx.x;
  const int tx = tid & 15, ty = tid >> 4;
  if (tid < BM) {
    s_rm[tid] = rmax[b * LL + l0 + tid];
    s_ri[tid] = rinv[b * LL + l0 + tid];
    s_m1[tid] = mask1[b * LL + l0 + tid];
  }
  __syncthreads();
  const int al = tid & 127, akg = (tid >> 7) * 4;
  const int cc = (tid & 31) * 4, kk_ = tid >> 5;

  float acc[8][8] = {};
  for (int k0 = 0; k0 < LL; k0 += KT) {
    float4 ev = *(const float4*)(e + (size_t)(l0 + al) * LL + k0 + akg);
    float4 mk = *(const float4*)(mask2 + b * LL + k0 + akg);
    const float rm = s_rm[al], ri = s_ri[al];
    sA[akg + 0][al] = __expf(ev.x * mk.x - rm) * ri;
    sA[akg + 1][al] = __expf(ev.y * mk.y - rm) * ri;
    sA[akg + 2][al] = __expf(ev.z * mk.z - rm) * ri;
    sA[akg + 3][al] = __expf(ev.w * mk.w - rm) * ri;
    const int gd = d0 + cc;
    float4 bv = make_float4(0.f, 0.f, 0.f, 0.f);
    if (gd < INP) bv = *(const float4*)(s2 + (size_t)(k0 + kk_) * INP + gd);
    *(float4*)&sB[kk_][cc] = bv;
    __syncthreads();
    micro_8x8(sA, sB, acc, tx, ty);
    __syncthreads();
  }
#pragma unroll
  for (int i = 0; i < 8; ++i) {
    const int l = l0 + ty * 8 + i;
    const float mm = s_m1[ty * 8 + i];
    float* orow = OutB + ((size_t)b * LL + l) * INP;
#pragma unroll
    for (int j4 = 0; j4 < 8; j4 += 4) {
      const int d = d0 + tx * 8 + j4;
      if (d < INP) {
        *(float4*)(orow + d) = make_float4(acc[i][j4] * mm, acc[i][j4 + 1] * mm,
                                           acc[i][j4 + 2] * mm, acc[i][j4 + 3] * mm);
      }
    }
  }
}

} // namespace

extern "C" void kernel_launch(void* const* d_in, const int* in_sizes, int n_in,
                              void* d_out, int out_size, void* d_ws, size_t ws_size,
                              hipStream_t stream)
{
  const float* s1    = (const float*)d_in[0];
  const float* s2    = (const float*)d_in[1];
  const float* mask1 = (const float*)d_in[2];
  const float* mask2 = (const float*)d_in[3];
  const float* W1    = (const float*)d_in[4];
  const float* b1    = (const float*)d_in[5];
  const float* W2    = (const float*)d_in[6];
  const float* b2    = (const float*)d_in[7];

  char* ws = (char*)d_ws;
  float* outA = (float*)d_out;
  float* outB = outA + (size_t)BB * LL * INP;

  // -------- fast-path workspace layout (bytes), lifetime-packed (identical to r5/r6) --------
  const size_t off_splo = 83886080;
  const size_t off_hmid = 167772160;
  const size_t off_wt   = 234881024;
  const size_t off_E    = 104857600;
  const size_t off_Pb   = 239075328;
  const size_t TOTAL    = 306184192;

  if (ws_size >= TOTAL) {
    unsigned short* sp_hi = (unsigned short*)(ws + 0);
    unsigned short* sp_lo = (unsigned short*)(ws + off_splo);
    unsigned short* hmid_hi = (unsigned short*)(ws + off_hmid);
    unsigned short* hmid_lo = hmid_hi + (size_t)2 * RS * KP2;
    unsigned short* Wt1hi = (unsigned short*)(ws + off_wt);
    unsigned short* Wt1lo = Wt1hi + (size_t)256 * KP1;
    unsigned short* Wt2hi = Wt1lo + (size_t)256 * KP1;
    unsigned short* Wt2lo = Wt2hi + (size_t)256 * KP2;
    unsigned short* h_hi = (unsigned short*)(ws + 0);
    unsigned short* h_lo = h_hi + (size_t)2 * RS * KP2;
    float* E = (float*)(ws + off_E);
    unsigned short* Pb = (unsigned short*)(ws + off_Pb);
    unsigned short* Pa = (unsigned short*)(ws + 0);
    float* stats = (float*)(ws + 67108864);
    float* cmax = stats;
    float* cinv = cmax + RS;
    float* pmax = cinv + RS;
    float* psum = pmax + (size_t)BB * 4 * LL;
    unsigned short* s1t = (unsigned short*)(ws + off_E);
    unsigned short* s2t = s1t + (size_t)BB * DPAD * LL;

    // 1) prep: split weights and inputs
    wt_prep<<<dim3(3, 256), 256, 0, stream>>>(W1, Wt1hi, Wt1lo, INP, KP1);
    wt_prep<<<dim3(1, 256), 256, 0, stream>>>(W2, Wt2hi, Wt2lo, HID, KP2);
    presplit<<<dim3((2 * RS * 160) / 256), 256, 0, stream>>>(s1, s2, sp_hi, sp_lo);
    // 2) MLP layer 1: hmid = relu(s @ W1 + b1), split output
    splitmm2<true><<<dim3(RS / 128, 2, 2), 256, 0, stream>>>(
        sp_hi, sp_lo, (long)RS * KP1, KP1,
        Wt1hi, Wt1lo, 0, KP1, 10, b1,
        hmid_hi, hmid_lo, nullptr, KP2, (long)RS * KP2);
    // 3) MLP layer 2: h = relu(hmid @ W2 + b2), split output
    splitmm2<true><<<dim3(RS / 128, 2, 2), 256, 0, stream>>>(
        hmid_hi, hmid_lo, (long)RS * KP2, KP2,
        Wt2hi, Wt2lo, 0, KP2, 4, b2,
        h_hi, h_lo, nullptr, KP2, (long)RS * KP2);
    // 4) e = h1 @ h2^T (XCD-swizzled 1D grid: 2048 = 8*256, 64 blocks/batch co-XCD)
    splitmm2<false><<<dim3(2048), 256, 0, stream>>>(
        h_hi, h_lo, (long)LL * KP2, KP2,
        h_hi + (size_t)RS * KP2, h_lo + (size_t)RS * KP2, (long)LL * KP2, KP2, 4, nullptr,
        nullptr, nullptr, E, LL, (long)LL * LL);
    // 5) softmax stats + P matrices
    row_stats_pbeta<<<dim3(RS / 4), 256, 0, stream>>>(E, mask2, Pb);
    col_stats_p1<<<dim3(4, 4, BB), 256, 0, stream>>>(E, mask1, pmax, psum);
    col_stats_p2<<<dim3(4, BB), 256, 0, stream>>>(pmax, psum, cmax, cinv);
    palpha_kernel<<<dim3(16, 16, BB), 256, 0, stream>>>(E, mask1, cmax, cinv, Pa);  // E dead
    // 6) s transposes (overlay E region)
    s_transpose<<<dim3(10, 16, BB), 256, 0, stream>>>(s1, s1t);
    s_transpose<<<dim3(10, 16, BB), 256, 0, stream>>>(s2, s2t);
    // 7) outputs (XCD-swizzled 1D grid: 1280 = 8*160, 40 blocks/batch co-XCD)
    attn_gemm_bf16<<<dim3(1280), 256, 0, stream>>>(Pb, s2t, mask1, outB);
    attn_gemm_bf16<<<dim3(1280), 256, 0, stream>>>(Pa, s1t, mask2, outA);
  } else {
    // -------- fallback: round-1 fp32 path (188 MB) --------
    float* h    = (float*)ws;
    float* hmid = h + (size_t)2 * RS * HID;
    float* E    = hmid;
    float* stats = hmid + (size_t)BB * LL * LL;
    float* rmax = stats;
    float* rinv = rmax + RS;
    float* cmax = rinv + RS;
    float* cinv = cmax + RS;
    float* pmax = cinv + RS;
    float* psum = pmax + (size_t)BB * 4 * LL;

    mlp_gemm<<<dim3(RS / BM, 2, 2), 256, 0, stream>>>(s1, s2, W1, b1, hmid, INP);
    mlp_gemm<<<dim3(RS / BM, 2, 2), 256, 0, stream>>>(hmid, hmid + (size_t)RS * HID, W2, b2, h, HID);
    e_gemm<<<dim3(LL / BM, LL / BN, BB), 256, 0, stream>>>(h, h + (size_t)RS * HID, E);
    row_stats<<<dim3(RS / 4), 256, 0, stream>>>(E, mask2, rmax, rinv);
    col_stats_p1<<<dim3(4, 4, BB), 256, 0, stream>>>(E, mask1, pmax, psum);
    col_stats_p2<<<dim3(4, BB), 256, 0, stream>>>(pmax, psum, cmax, cinv);
    alphas_gemm<<<dim3(LL / BM, (INP + BN - 1) / BN, BB), 256, 0, stream>>>(
        E, s1, mask1, mask2, cmax, cinv, outA);
    betas_gemm<<<dim3(LL / BM, (INP + BN - 1) / BN, BB), 256, 0, stream>>>(
        E, s2, mask1, mask2, rmax, rinv, outB);
  }

  (void)in_sizes; (void)n_in; (void)out_size;
}